// Round 5
// baseline (124.929 us; speedup 1.0000x reference)
//
#include <hip/hip_runtime.h>

#define DIM 512
#define HID 2048
#define NEXP 8

typedef __attribute__((ext_vector_type(8))) short v8s;   // 8 x bf16 bits
typedef __attribute__((ext_vector_type(4))) float v4f;   // MFMA accumulator

__device__ __forceinline__ unsigned short f2bf(float f) {
  union { __bf16 b; unsigned short u; } c;
  c.b = (__bf16)f;
  return c.u;
}

__device__ __forceinline__ void gload16(const void* g, void* l) {
  __builtin_amdgcn_global_load_lds(
      (const __attribute__((address_space(1))) unsigned int*)g,
      (__attribute__((address_space(3))) unsigned int*)l, 16, 0, 0);
}

// ---------------- routing prep ----------------
__global__ void route_prep(const int* __restrict__ route, int* __restrict__ meta, int ntok) {
  __shared__ int c[NEXP];
  int t = threadIdx.x;
  if (t < NEXP) c[t] = 0;
  __syncthreads();
  for (int n = t; n < ntok; n += blockDim.x) atomicAdd(&c[route[n]], 1);
  __syncthreads();
  if (t == 0) {
    int acc = 0, pacc = 0;
    for (int e = 0; e < NEXP; ++e) {
      meta[e] = c[e];            // count
      meta[NEXP + e] = acc;      // exact offset
      meta[2 * NEXP + e] = acc;  // cursor for fill_perm
      meta[3 * NEXP + e] = pacc; // 128-padded offset (panel rows)
      acc += c[e];
      pacc += ((c[e] + 127) >> 7) << 7;
    }
  }
}

__global__ void fill_perm(const int* __restrict__ route, int* __restrict__ meta,
                          int* __restrict__ perm, int ntok) {
  int n = blockIdx.x * blockDim.x + threadIdx.x;
  if (n < ntok) {
    int p = atomicAdd(&meta[2 * NEXP + route[n]], 1);
    perm[p] = n;
  }
}

// ---------------- x conversion: gathered bf16 A-panels ----------------
// xp per 64-row tile: [kq 0..63][row 0..63][8k] bf16 = 32768 ushorts (64 KB).
__global__ __launch_bounds__(256) void x_conv(
    const float* __restrict__ x, const int* __restrict__ meta,
    const int* __restrict__ perm, unsigned short* __restrict__ xp)
{
  const int bid = blockIdx.x;
  const int e = bid & 7;
  const int mt = bid >> 3;
  const int cnt = meta[e];
  if (mt * 64 >= cnt) return;
  const int off  = meta[NEXP + e];
  const int poff = meta[3 * NEXP + e];
  const int t = threadIdx.x;
  const int r = t & 63, q = t >> 6;          // row, quarter (128 floats)
  int arow = mt * 64 + r; if (arow >= cnt) arow = cnt - 1;
  const float* src = x + (size_t)perm[off + arow] * DIM + q * 128;
  unsigned short* dst = xp + (size_t)((poff + mt * 64) >> 6) * 32768;
  #pragma unroll
  for (int j = 0; j < 16; ++j) {
    float4 f0 = ((const float4*)src)[2 * j];
    float4 f1 = ((const float4*)src)[2 * j + 1];
    v8s v;
    v[0] = (short)f2bf(f0.x); v[1] = (short)f2bf(f0.y);
    v[2] = (short)f2bf(f0.z); v[3] = (short)f2bf(f0.w);
    v[4] = (short)f2bf(f1.x); v[5] = (short)f2bf(f1.y);
    v[6] = (short)f2bf(f1.z); v[7] = (short)f2bf(f1.w);
    *(v8s*)(dst + (size_t)((q * 16 + j) * 64 + r) * 8) = v;
  }
}

// ---------------- w_out conversion (unchanged, R=64 panels) ----------------
__global__ __launch_bounds__(256) void wo_conv(
    const float* __restrict__ wo, unsigned short* __restrict__ wop)
{
  const int s = blockIdx.x;            // 64-K chunk (32)
  const int j = blockIdx.y;            // n-stripe (8)
  const int e = blockIdx.z;
  const float* src = wo + (size_t)e * HID * DIM;
  unsigned short* dst = wop + (((size_t)e * 8 + j) * 32 + s) * 4096;
  const int t = threadIdx.x;
  #pragma unroll
  for (int i = 0; i < 2; ++i) {
    const int c = t + 256 * i;         // chunk in [0,512)
    const int kq = c >> 6, n = c & 63;
    const float* srow = src + (size_t)(s * 64 + kq * 8) * DIM + j * 64 + n;
    v8s r;
    #pragma unroll
    for (int q = 0; q < 8; ++q) r[q] = (short)f2bf(srow[(size_t)q * DIM]);
    *(v8s*)(dst + (size_t)c * 8) = r;
  }
}

// ---------------- GEMM1 fused: persistent LDS weights ----------------
// Block = (expert, 64-col n-stripe). Converts wg/wi f32 slab -> 2x64KB LDS
// panels ONCE, then loops expert's 256-row M-tiles streaming x via gload16.
// 4 waves, wave tile 64x64 on BOTH matrices (A-frags shared): 12 ds_read_b128
// per 32 MFMA per 32k step. LDS = 160 KB exactly.
__global__ __launch_bounds__(256, 1) void gemm1f(
    const unsigned short* __restrict__ xp,
    const float* __restrict__ wg_, const float* __restrict__ bg_,
    const float* __restrict__ wi_, const float* __restrict__ bi_,
    const int* __restrict__ meta,
    unsigned short* __restrict__ hbuf)
{
  const int bid = blockIdx.x;
  const int e = bid & 7;               // XCD swizzle: expert per XCD
  const int j = bid >> 3;              // 0..31 (n-stripe of 64)
  const int n0 = j * 64;
  const int cnt = meta[e];
  const int poff = meta[3 * NEXP + e];

  // G panel 64K | I panel 64K | x dbuf 2x16K  = 163840 B
  __shared__ __align__(16) unsigned char lds[163840];

  const int t = threadIdx.x;
  const int l = t & 63, w = t >> 6;    // 4 waves
  const int fr = l & 15, fg = l >> 4;

  // ---- one-time weight convert: [kq 0..63][n 0..63][8] bf16 ----
  {
    const float* wg = wg_ + (size_t)e * DIM * HID + n0 + l;
    const float* wi = wi_ + (size_t)e * DIM * HID + n0 + l;
    #pragma unroll 4
    for (int it = 0; it < 16; ++it) {
      const int kq = w + 4 * it;       // 0..63
      const float* s0 = wg + (size_t)(kq * 8) * HID;
      const float* s1 = wi + (size_t)(kq * 8) * HID;
      v8s r0, r1;
      #pragma unroll
      for (int q = 0; q < 8; ++q) {
        r0[q] = (short)f2bf(s0[(size_t)q * HID]);
        r1[q] = (short)f2bf(s1[(size_t)q * HID]);
      }
      *(v8s*)(lds + (kq * 64 + l) * 16) = r0;
      *(v8s*)(lds + 65536 + (kq * 64 + l) * 16) = r1;
    }
  }
  __syncthreads();

  unsigned char* xlds = lds + 131072;
  const int tile0 = poff >> 6;
  const int nmt = (cnt + 255) >> 8;

  for (int mt = 0; mt < nmt; ++mt) {
    const int m0 = mt * 256;
    const size_t xbase = (size_t)(tile0 + (m0 >> 6)) * 32768;

    // stage: wave w stages 64-row tile tt=w, kq chunk i; 4 gload16/thread
    auto stage_x = [&](int s, int b) {
      #pragma unroll
      for (int i = 0; i < 4; ++i)
        gload16(xp + xbase + (size_t)w * 32768 + ((s * 4 + i) * 64 + l) * 8,
                xlds + b * 16384 + (w * 64 + 256 * i) * 16);
    };

    stage_x(0, 0);
    __syncthreads();

    v4f aG[4][4], aI[4][4];
    #pragma unroll
    for (int i = 0; i < 4; ++i)
      #pragma unroll
      for (int q = 0; q < 4; ++q) {
        aG[i][q] = (v4f){0.f, 0.f, 0.f, 0.f};
        aI[i][q] = (v4f){0.f, 0.f, 0.f, 0.f};
      }

    int cur = 0;
    for (int s = 0; s < 16; ++s) {     // K = 512 in 32-wide steps
      if (s < 15) stage_x(s + 1, cur ^ 1);
      const unsigned char* xb = xlds + cur * 16384;
      v8s af[4], gf[4], inf[4];
      #pragma unroll
      for (int mf = 0; mf < 4; ++mf)
        af[mf] = *(const v8s*)(xb + (fg * 256 + w * 64 + mf * 16 + fr) * 16);
      #pragma unroll
      for (int nf = 0; nf < 4; ++nf) {
        gf[nf]  = *(const v8s*)(lds + ((s * 4 + fg) * 64 + nf * 16 + fr) * 16);
        inf[nf] = *(const v8s*)(lds + 65536 + ((s * 4 + fg) * 64 + nf * 16 + fr) * 16);
      }
      #pragma unroll
      for (int mf = 0; mf < 4; ++mf)
        #pragma unroll
        for (int nf = 0; nf < 4; ++nf) {
          aG[mf][nf] = __builtin_amdgcn_mfma_f32_16x16x32_bf16(af[mf], gf[nf],  aG[mf][nf], 0, 0, 0);
          aI[mf][nf] = __builtin_amdgcn_mfma_f32_16x16x32_bf16(af[mf], inf[nf], aI[mf][nf], 0, 0, 0);
        }
      __syncthreads();
      cur ^= 1;
    }

    // epilogue: bias + SiLU(gate)*in -> hbuf panels
    #pragma unroll
    for (int nf = 0; nf < 4; ++nf) {
      const int c = n0 + nf * 16 + fr;
      const float bg = bg_[(size_t)e * HID + c];
      const float bi = bi_[(size_t)e * HID + c];
      #pragma unroll
      for (int mf = 0; mf < 4; ++mf)
        #pragma unroll
        for (int jj = 0; jj < 4; ++jj) {
          const int r = w * 64 + mf * 16 + fg * 4 + jj;
          if (m0 + r < cnt) {
            const float g = aG[mf][nf][jj] + bg;
            const float v = aI[mf][nf][jj] + bi;
            const float hval = g / (1.f + __expf(-g)) * v;
            const int grow = poff + m0 + r;
            hbuf[(size_t)(grow >> 6) * 131072 + ((c >> 3) * 64 + (grow & 63)) * 8 + (c & 7)] = f2bf(hval);
          }
        }
    }
  }
}

// ---------------- GEMM2: out[perm] = h @ w_out + b_out ----------------
// BM=128, BN=64, BK=64, 256 thr (4 waves 2x2, wave 64x32), dbuf 2x24KB,
// 3 blocks/CU, all staging via gload16.
__global__ __launch_bounds__(256, 3) void gemm2n(
    const unsigned short* __restrict__ hbuf,
    const unsigned short* __restrict__ wop, const float* __restrict__ bo_,
    const int* __restrict__ meta, const int* __restrict__ perm,
    float* __restrict__ out)
{
  const int bid = blockIdx.x;
  const int e = bid & 7;
  const int r_ = bid >> 3;
  const int jn = r_ & 7;       // n-stripe of 64
  const int mt = r_ >> 3;      // M-tile of 128
  const int cnt = meta[e];
  const int m0 = mt * 128;
  if (m0 >= cnt) return;
  const int off = meta[NEXP + e], poff = meta[3 * NEXP + e];
  const int n0 = jn * 64;

  // 2 x ( A 16K | B 8K )
  __shared__ __align__(16) unsigned char lds[49152];

  const int t = threadIdx.x;
  const int l = t & 63, w = t >> 6;
  const int wm = w >> 1, wn = w & 1;
  const int fr = l & 15, fg = l >> 4;

  const size_t abase = (size_t)((poff + m0) >> 6) * 131072;
  const unsigned short* pb = wop + ((size_t)e * 8 + jn) * 131072;

  v4f acc[4][2];
  #pragma unroll
  for (int i = 0; i < 4; ++i) {
    acc[i][0] = (v4f){0.f, 0.f, 0.f, 0.f};
    acc[i][1] = (v4f){0.f, 0.f, 0.f, 0.f};
  }

  auto stage = [&](int s, int b) {
    unsigned char* base = lds + b * 24576;
    #pragma unroll
    for (int i = 0; i < 4; ++i) {      // A: 16 KB, tile tt = w&1, kq = (4i+w)>>1
      const int kq = (4 * i + w) >> 1;
      gload16(hbuf + abase + (size_t)(w & 1) * 131072 + ((s * 8 + kq) * 64 + l) * 8,
              base + (w * 64 + 256 * i) * 16);
    }
    #pragma unroll
    for (int i = 0; i < 2; ++i)        // B: 8 KB
      gload16(pb + (size_t)s * 4096 + (t + 256 * i) * 8,
              base + 16384 + (w * 64 + 256 * i) * 16);
  };

  stage(0, 0);
  __syncthreads();

  int cur = 0;
  for (int s = 0; s < 32; ++s) {       // K = 2048 in 64-wide steps
    if (s < 31) stage(s + 1, cur ^ 1);
    unsigned char* base = lds + cur * 24576;
    v8s af[2][4], bf[2][2];
    #pragma unroll
    for (int kk = 0; kk < 2; ++kk) {
      #pragma unroll
      for (int mf = 0; mf < 4; ++mf)
        af[kk][mf] = *(const v8s*)(base + ((kk * 4 + fg) * 128 + wm * 64 + mf * 16 + fr) * 16);
      #pragma unroll
      for (int nf = 0; nf < 2; ++nf)
        bf[kk][nf] = *(const v8s*)(base + 16384 + ((kk * 4 + fg) * 64 + wn * 32 + nf * 16 + fr) * 16);
    }
    #pragma unroll
    for (int kk = 0; kk < 2; ++kk)
      #pragma unroll
      for (int mf = 0; mf < 4; ++mf)
        #pragma unroll
        for (int nf = 0; nf < 2; ++nf)
          acc[mf][nf] = __builtin_amdgcn_mfma_f32_16x16x32_bf16(af[kk][mf], bf[kk][nf], acc[mf][nf], 0, 0, 0);
    __syncthreads();
    cur ^= 1;
  }

  #pragma unroll
  for (int nf = 0; nf < 2; ++nf) {
    const int c = n0 + wn * 32 + nf * 16 + fr;
    const float bo = bo_[(size_t)e * DIM + c];
    #pragma unroll
    for (int mf = 0; mf < 4; ++mf)
      #pragma unroll
      for (int jj = 0; jj < 4; ++jj) {
        const int r = wm * 64 + mf * 16 + fg * 4 + jj;
        if (m0 + r < cnt)
          out[(size_t)perm[off + m0 + r] * DIM + c] = acc[mf][nf][jj] + bo;
      }
  }
}

// ---------------- launch ----------------
extern "C" void kernel_launch(void* const* d_in, const int* in_sizes, int n_in,
                              void* d_out, int out_size, void* d_ws, size_t ws_size,
                              hipStream_t stream) {
  const float* x      = (const float*)d_in[0];
  const int*   route  = (const int*)d_in[1];
  const float* w_in   = (const float*)d_in[2];
  const float* b_in   = (const float*)d_in[3];
  const float* w_gate = (const float*)d_in[4];
  const float* b_gate = (const float*)d_in[5];
  const float* w_out  = (const float*)d_in[6];
  const float* b_out  = (const float*)d_in[7];
  float* out = (float*)d_out;

  const int ntok = in_sizes[1];  // 4096

  int* meta = (int*)d_ws;
  int* perm = (int*)((char*)d_ws + 128);

  // ws: meta/perm | xp 5.25MB | wop 32MB | hbuf 21MB  (~57.1 MB total)
  unsigned short* xp   = (unsigned short*)((char*)d_ws + 65536);
  unsigned short* wop  = (unsigned short*)((char*)d_ws + 65536 + 5242880);
  unsigned short* hbuf = (unsigned short*)((char*)d_ws + 65536 + 5242880 + 33554432);

  const int MT64  = (ntok + 63) / 64;
  const int MT128 = (ntok + 127) / 128;

  route_prep<<<1, 256, 0, stream>>>(route, meta, ntok);
  fill_perm<<<(ntok + 255) / 256, 256, 0, stream>>>(route, meta, perm, ntok);
  x_conv<<<NEXP * MT64, 256, 0, stream>>>(x, meta, perm, xp);
  gemm1f<<<NEXP * 32, 256, 0, stream>>>(
      xp, w_gate, b_gate, w_in, b_in, meta, hbuf);
  wo_conv<<<dim3(32, 8, 8), 256, 0, stream>>>(w_out, wop);
  gemm2n<<<NEXP * 8 * MT128, 256, 0, stream>>>(
      hbuf, wop, b_out, meta, perm, out);
}

// Round 6
// 110.490 us; speedup vs baseline: 1.1307x; 1.1307x over previous
//
#include <hip/hip_runtime.h>

#define DIM 512
#define HID 2048
#define NEXP 8

typedef __attribute__((ext_vector_type(8))) short v8s;   // 8 x bf16 bits
typedef __attribute__((ext_vector_type(4))) float v4f;   // MFMA accumulator

__device__ __forceinline__ unsigned short f2bf(float f) {
  union { __bf16 b; unsigned short u; } c;
  c.b = (__bf16)f;
  return c.u;
}

__device__ __forceinline__ void gload16(const void* g, void* l) {
  __builtin_amdgcn_global_load_lds(
      (const __attribute__((address_space(1))) unsigned int*)g,
      (__attribute__((address_space(3))) unsigned int*)l, 16, 0, 0);
}

// ---------------- routing prep ----------------
__global__ void route_prep(const int* __restrict__ route, int* __restrict__ meta, int ntok) {
  __shared__ int c[NEXP];
  int t = threadIdx.x;
  if (t < NEXP) c[t] = 0;
  __syncthreads();
  for (int n = t; n < ntok; n += blockDim.x) atomicAdd(&c[route[n]], 1);
  __syncthreads();
  if (t == 0) {
    int acc = 0, pacc = 0;
    for (int e = 0; e < NEXP; ++e) {
      meta[e] = c[e];            // count
      meta[NEXP + e] = acc;      // exact offset
      meta[2 * NEXP + e] = acc;  // cursor for fill_perm
      meta[3 * NEXP + e] = pacc; // 128-padded offset (panel rows)
      acc += c[e];
      pacc += ((c[e] + 127) >> 7) << 7;
    }
  }
}

__global__ void fill_perm(const int* __restrict__ route, int* __restrict__ meta,
                          int* __restrict__ perm, int ntok) {
  int n = blockIdx.x * blockDim.x + threadIdx.x;
  if (n < ntok) {
    int p = atomicAdd(&meta[2 * NEXP + route[n]], 1);
    perm[p] = n;
  }
}

// ---------------- x conversion: gathered bf16 A-panels ----------------
// xp per 64-row tile: [kq 0..63][row 0..63][8k] bf16 = 32768 ushorts (64 KB).
__global__ __launch_bounds__(256) void x_conv(
    const float* __restrict__ x, const int* __restrict__ meta,
    const int* __restrict__ perm, unsigned short* __restrict__ xp)
{
  const int bid = blockIdx.x;
  const int e = bid & 7;
  const int mt = bid >> 3;
  const int cnt = meta[e];
  if (mt * 64 >= cnt) return;
  const int off  = meta[NEXP + e];
  const int poff = meta[3 * NEXP + e];
  const int t = threadIdx.x;
  const int r = t & 63, q = t >> 6;          // row, quarter (128 floats)
  int arow = mt * 64 + r; if (arow >= cnt) arow = cnt - 1;  // clamp (dup rows)
  const float* src = x + (size_t)perm[off + arow] * DIM + q * 128;
  unsigned short* dst = xp + (size_t)((poff + mt * 64) >> 6) * 32768;
  #pragma unroll
  for (int j = 0; j < 16; ++j) {
    float4 f0 = ((const float4*)src)[2 * j];
    float4 f1 = ((const float4*)src)[2 * j + 1];
    v8s v;
    v[0] = (short)f2bf(f0.x); v[1] = (short)f2bf(f0.y);
    v[2] = (short)f2bf(f0.z); v[3] = (short)f2bf(f0.w);
    v[4] = (short)f2bf(f1.x); v[5] = (short)f2bf(f1.y);
    v[6] = (short)f2bf(f1.z); v[7] = (short)f2bf(f1.w);
    *(v8s*)(dst + (size_t)((q * 16 + j) * 64 + r) * 8) = v;
  }
}

// ---------------- GEMM1: h = silu(x@wg+bg)*(x@wi+bi) -> hbuf panels ----------------
// BM=64, BN=128, BK=32, 256 thr (4 waves 2x2: wave 32m x 64n, both matrices).
// A via gload16 from xp panels; weights reg-staged f32->bf16 in-loop (T14 split:
// strided loads issued before MFMA, cvt+ds_write after). dbuf 2x20KB, 3 blk/CU.
__global__ __launch_bounds__(256, 3) void gemm1r(
    const unsigned short* __restrict__ xp,
    const float* __restrict__ wg_, const float* __restrict__ bg_,
    const float* __restrict__ wi_, const float* __restrict__ bi_,
    const int* __restrict__ meta,
    unsigned short* __restrict__ hbuf)
{
  const int bid = blockIdx.x;
  const int e = bid & 7;               // XCD swizzle
  const int r_ = bid >> 3;
  const int j = r_ & 15;               // n-stripe of 128
  const int mt = r_ >> 4;              // 64-row M-tile
  const int cnt = meta[e];
  const int m0 = mt * 64;
  if (m0 >= cnt) return;
  const int poff = meta[3 * NEXP + e];
  const int n0 = j * 128;

  // per buf (20480 B): A @0 (4K) | G @4096 (8K) | I @12288 (8K)
  __shared__ __align__(16) unsigned char lds[40960];

  const int t = threadIdx.x;
  const int l = t & 63, w = t >> 6;
  const int wm = w >> 1, wn = w & 1;
  const int fr = l & 15, fg = l >> 4;

  const unsigned short* pa = xp + (size_t)((poff + m0) >> 6) * 32768;
  const float* wg = wg_ + (size_t)e * DIM * HID + n0;
  const float* wi = wi_ + (size_t)e * DIM * HID + n0;

  // weight staging slots: slot = kq*128 + n; thread owns slots t and t+256.
  const int s_kq = t >> 7;             // 0..1 (second slot: +2)
  const int s_n  = t & 127;

  v4f aG[2][4], aI[2][4];
  #pragma unroll
  for (int i = 0; i < 2; ++i)
    #pragma unroll
    for (int q = 0; q < 4; ++q) {
      aG[i][q] = (v4f){0.f, 0.f, 0.f, 0.f};
      aI[i][q] = (v4f){0.f, 0.f, 0.f, 0.f};
    }

  float stG0[8], stG1[8], stI0[8], stI1[8];

  auto wload = [&](int s) {            // issue 32 strided f32 loads (per-wave coalesced rows)
    const size_t b0 = (size_t)(s * 32 + s_kq * 8) * HID + s_n;
    const size_t b1 = (size_t)(s * 32 + (s_kq + 2) * 8) * HID + s_n;
    #pragma unroll
    for (int q = 0; q < 8; ++q) {
      stG0[q] = wg[b0 + (size_t)q * HID];
      stG1[q] = wg[b1 + (size_t)q * HID];
      stI0[q] = wi[b0 + (size_t)q * HID];
      stI1[q] = wi[b1 + (size_t)q * HID];
    }
  };
  auto wstore = [&](int b) {           // cvt + panel ds_write
    unsigned char* base = lds + b * 20480;
    v8s g0, g1, i0, i1;
    #pragma unroll
    for (int q = 0; q < 8; ++q) {
      g0[q] = (short)f2bf(stG0[q]); g1[q] = (short)f2bf(stG1[q]);
      i0[q] = (short)f2bf(stI0[q]); i1[q] = (short)f2bf(stI1[q]);
    }
    *(v8s*)(base + 4096  + (s_kq * 128 + s_n) * 16)       = g0;
    *(v8s*)(base + 4096  + ((s_kq + 2) * 128 + s_n) * 16) = g1;
    *(v8s*)(base + 12288 + (s_kq * 128 + s_n) * 16)       = i0;
    *(v8s*)(base + 12288 + ((s_kq + 2) * 128 + s_n) * 16) = i1;
  };
  auto aload = [&](int s, int b) {     // A: [kq=w][m=l][8k], 1 gload16/thread
    gload16(pa + ((size_t)(s * 4 + w) * 64 + l) * 8, lds + b * 20480 + t * 16);
  };

  // prologue
  wload(0);
  aload(0, 0);
  wstore(0);
  __syncthreads();

  int cur = 0;
  for (int s = 0; s < 16; ++s) {       // K = 512 in 32-wide steps
    if (s < 15) { wload(s + 1); aload(s + 1, cur ^ 1); }  // issue early (T14)
    const unsigned char* base = lds + cur * 20480;
    v8s af[2], gf[4], inf[4];
    #pragma unroll
    for (int mf = 0; mf < 2; ++mf)
      af[mf] = *(const v8s*)(base + (fg * 64 + wm * 32 + mf * 16 + fr) * 16);
    #pragma unroll
    for (int nf = 0; nf < 4; ++nf) {
      gf[nf]  = *(const v8s*)(base + 4096  + (fg * 128 + wn * 64 + nf * 16 + fr) * 16);
      inf[nf] = *(const v8s*)(base + 12288 + (fg * 128 + wn * 64 + nf * 16 + fr) * 16);
    }
    #pragma unroll
    for (int mf = 0; mf < 2; ++mf)
      #pragma unroll
      for (int nf = 0; nf < 4; ++nf) {
        aG[mf][nf] = __builtin_amdgcn_mfma_f32_16x16x32_bf16(af[mf], gf[nf],  aG[mf][nf], 0, 0, 0);
        aI[mf][nf] = __builtin_amdgcn_mfma_f32_16x16x32_bf16(af[mf], inf[nf], aI[mf][nf], 0, 0, 0);
      }
    if (s < 15) wstore(cur ^ 1);       // cvt+write after MFMA (latency hidden)
    __syncthreads();
    cur ^= 1;
  }

  // epilogue: bias + SiLU(gate)*in -> hbuf panels (unguarded: padded rows are
  // deterministic via x_conv's clamped duplicate rows)
  const size_t tb = (size_t)((poff + m0) >> 6) * 131072;
  #pragma unroll
  for (int nf = 0; nf < 4; ++nf) {
    const int c = n0 + wn * 64 + nf * 16 + fr;        // k-dim of gemm2
    const float bg = bg_[(size_t)e * HID + c];
    const float bi = bi_[(size_t)e * HID + c];
    #pragma unroll
    for (int mf = 0; mf < 2; ++mf)
      #pragma unroll
      for (int jj = 0; jj < 4; ++jj) {
        const int r = wm * 32 + mf * 16 + fg * 4 + jj;  // 0..63
        const float g = aG[mf][nf][jj] + bg;
        const float v = aI[mf][nf][jj] + bi;
        const float hval = g / (1.f + __expf(-g)) * v;
        hbuf[tb + (size_t)((c >> 3) * 64 + r) * 8 + (c & 7)] = f2bf(hval);
      }
  }
}

// ---------------- GEMM2: out[perm] = h @ w_out + b_out ----------------
// BM=64, BN=32, BK=64, 256 thr (4 waves 2x2: wave 32m x 16n).
// A via gload16 from hbuf panels; w_out reg-staged f32->bf16 in-loop.
// dbuf 2x12KB, 4+ blk/CU, grid 1024 active.
__global__ __launch_bounds__(256, 4) void gemm2r(
    const unsigned short* __restrict__ hbuf,
    const float* __restrict__ wo_, const float* __restrict__ bo_,
    const int* __restrict__ meta, const int* __restrict__ perm,
    float* __restrict__ out)
{
  const int bid = blockIdx.x;
  const int e = bid & 7;
  const int r_ = bid >> 3;
  const int jn = r_ & 15;              // n-stripe of 32
  const int mt = r_ >> 4;              // 64-row M-tile
  const int cnt = meta[e];
  const int m0 = mt * 64;
  if (m0 >= cnt) return;
  const int off = meta[NEXP + e], poff = meta[3 * NEXP + e];
  const int n0 = jn * 32;

  // per buf (12288 B): A @0 (8K) | B @8192 (4K)
  __shared__ __align__(16) unsigned char lds[24576];

  const int t = threadIdx.x;
  const int l = t & 63, w = t >> 6;
  const int wm = w >> 1, wn = w & 1;
  const int fr = l & 15, fg = l >> 4;

  const unsigned short* pa = hbuf + (size_t)((poff + m0) >> 6) * 131072;
  const float* wo = wo_ + (size_t)e * HID * DIM + n0;

  // B staging slots: slot = kq*32 + n (kq 0..7, n 0..31); 1 slot/thread.
  const int b_kq = t >> 5, b_n = t & 31;

  v4f acc[2];
  acc[0] = (v4f){0.f, 0.f, 0.f, 0.f};
  acc[1] = (v4f){0.f, 0.f, 0.f, 0.f};

  float stB[8];
  auto bload = [&](int s) {
    const size_t b0 = (size_t)(s * 64 + b_kq * 8) * DIM + b_n;
    #pragma unroll
    for (int q = 0; q < 8; ++q) stB[q] = wo[b0 + (size_t)q * DIM];
  };
  auto bstore = [&](int b) {
    v8s r;
    #pragma unroll
    for (int q = 0; q < 8; ++q) r[q] = (short)f2bf(stB[q]);
    *(v8s*)(lds + b * 12288 + 8192 + (b_kq * 32 + b_n) * 16) = r;
  };
  auto aload = [&](int s, int b) {     // A: [kq 0..7][m 0..63][8k], 2 gload16/thread
    #pragma unroll
    for (int i = 0; i < 2; ++i)
      gload16(pa + (size_t)s * 4096 + ((size_t)(i * 4 + w) * 64 + l) * 8,
              lds + b * 12288 + ((i * 4 + w) * 64) * 16 + l * 16);
  };

  bload(0);
  aload(0, 0);
  bstore(0);
  __syncthreads();

  int cur = 0;
  for (int s = 0; s < 32; ++s) {       // K = 2048 in 64-wide steps
    if (s < 31) { bload(s + 1); aload(s + 1, cur ^ 1); }
    const unsigned char* base = lds + cur * 12288;
    v8s af[2][2], bf[2];
    #pragma unroll
    for (int kk = 0; kk < 2; ++kk) {
      #pragma unroll
      for (int mf = 0; mf < 2; ++mf)
        af[kk][mf] = *(const v8s*)(base + ((kk * 4 + fg) * 64 + wm * 32 + mf * 16 + fr) * 16);
      bf[kk] = *(const v8s*)(base + 8192 + ((kk * 4 + fg) * 32 + wn * 16 + fr) * 16);
    }
    #pragma unroll
    for (int kk = 0; kk < 2; ++kk)
      #pragma unroll
      for (int mf = 0; mf < 2; ++mf)
        acc[mf] = __builtin_amdgcn_mfma_f32_16x16x32_bf16(af[kk][mf], bf[kk], acc[mf], 0, 0, 0);
    if (s < 31) bstore(cur ^ 1);
    __syncthreads();
    cur ^= 1;
  }

  const int c = n0 + wn * 16 + fr;
  const float bo = bo_[(size_t)e * DIM + c];
  #pragma unroll
  for (int mf = 0; mf < 2; ++mf)
    #pragma unroll
    for (int jj = 0; jj < 4; ++jj) {
      const int r = wm * 32 + mf * 16 + fg * 4 + jj;
      if (m0 + r < cnt)
        out[(size_t)perm[off + m0 + r] * DIM + c] = acc[mf][jj] + bo;
    }
}

// ---------------- launch ----------------
extern "C" void kernel_launch(void* const* d_in, const int* in_sizes, int n_in,
                              void* d_out, int out_size, void* d_ws, size_t ws_size,
                              hipStream_t stream) {
  const float* x      = (const float*)d_in[0];
  const int*   route  = (const int*)d_in[1];
  const float* w_in   = (const float*)d_in[2];
  const float* b_in   = (const float*)d_in[3];
  const float* w_gate = (const float*)d_in[4];
  const float* b_gate = (const float*)d_in[5];
  const float* w_out  = (const float*)d_in[6];
  const float* b_out  = (const float*)d_in[7];
  float* out = (float*)d_out;

  const int ntok = in_sizes[1];  // 4096

  int* meta = (int*)d_ws;
  int* perm = (int*)((char*)d_ws + 128);

  // ws: meta/perm | xp 5.25MB | hbuf 21MB  (~26 MB total)
  unsigned short* xp   = (unsigned short*)((char*)d_ws + 65536);
  unsigned short* hbuf = (unsigned short*)((char*)d_ws + 65536 + 5242880);

  const int MT64 = (ntok + 63) / 64;

  route_prep<<<1, 256, 0, stream>>>(route, meta, ntok);
  fill_perm<<<(ntok + 255) / 256, 256, 0, stream>>>(route, meta, perm, ntok);
  x_conv<<<NEXP * MT64, 256, 0, stream>>>(x, meta, perm, xp);
  gemm1r<<<NEXP * 16 * MT64, 256, 0, stream>>>(
      xp, w_gate, b_gate, w_in, b_in, meta, hbuf);
  gemm2r<<<NEXP * 16 * MT64, 256, 0, stream>>>(
      hbuf, w_out, b_out, meta, perm, out);
}